// Round 12
// baseline (154.310 us; speedup 1.0000x reference)
//
#include <hip/hip_runtime.h>
#include <math.h>

// MultiHeadsGATLayer — algebraic reduction, 2 dispatches.
//   s_src[h][n] = x[n] . (W_heads[h] @ a_src[h]),  s_dst likewise
//   atts = lrelu(s_src[e0]+s_dst[e1]); mt = sum_h atts*lin_w + lin_b
//   out = colwise sparse softmax; non-edge cells exactly 0 (f32 underflow).
// K1: sequential NT zero-stream of the 268MB output (the ONLY fast write
//     pattern: R11 showed 128B/32KB-stride strips run ~2x slower) + scores.
// K2: block owns 32 columns — int4 dst scan at 1024 thr (16 waves/CU; R10's
//     256-thr geometry was latency-bound), LDS binning, shuffle-dedup
//     softmax, then scattered DWORD writes into the pre-zeroed output
//     (~34MB RFO+WB, proven cheap in R7). No global atomics, no fences
//     (R4/R9: cross-XCD protocols ~100x a kernel boundary).

#define ALPHA 0.2f
constexpr int S = 128;
constexpr int O = 64;
constexpr int H = 4;
constexpr int CAP = 128;          // slots per column (degree ~ Poisson(32))
constexpr int CPB = 32;           // columns per K2 block
constexpr int TPB = 1024;         // K2 threads per block
constexpr int SCORE_BLOCKS = 32;  // ceil(N/256)

typedef float vf4 __attribute__((ext_vector_type(4)));

// --- K1: per-node scores + NT zero-stream of the output ---
__global__ void __launch_bounds__(256) k1_prep(
    const float* __restrict__ x, const float* __restrict__ W, const float* __restrict__ a,
    float4* __restrict__ s_src4, float4* __restrict__ s_dst4,
    vf4* __restrict__ out4, int N, size_t n4tot)
{
    int tid = threadIdx.x;
    if (blockIdx.x < (unsigned)SCORE_BLOCKS) {
        __shared__ float wsbuf[2 * H * S];
        for (int t = tid; t < 2 * H * S; t += 256) {
            int which = t / (H * S);           // 0 = src half, 1 = dst half
            int hs = t % (H * S);
            int h = hs / S, s = hs % S;
            const float* Wr = W + ((size_t)h * S + s) * O;
            const float* av = a + h * 2 * O + which * O;
            float acc = 0.f;
            for (int o = 0; o < O; ++o) acc += Wr[o] * av[o];
            wsbuf[t] = acc;
        }
        __syncthreads();
        int n = blockIdx.x * 256 + tid;
        if (n < N) {
            const float* wsrc = wsbuf;
            const float* wdst = wsbuf + H * S;
            const float4* xr = (const float4*)(x + (size_t)n * S);
            float accs[H] = {0, 0, 0, 0}, accd[H] = {0, 0, 0, 0};
            for (int i = 0; i < S / 4; ++i) {
                float4 v = xr[i];
#pragma unroll
                for (int h = 0; h < H; ++h) {
                    const float* p = wsrc + h * S + i * 4;
                    const float* q = wdst + h * S + i * 4;
                    accs[h] += v.x * p[0] + v.y * p[1] + v.z * p[2] + v.w * p[3];
                    accd[h] += v.x * q[0] + v.y * q[1] + v.z * q[2] + v.w * q[3];
                }
            }
            s_src4[n] = make_float4(accs[0], accs[1], accs[2], accs[3]);
            s_dst4[n] = make_float4(accd[0], accd[1], accd[2], accd[3]);
        }
    } else {
        const vf4 z4 = {0.f, 0.f, 0.f, 0.f};
        size_t gt = (size_t)(blockIdx.x - SCORE_BLOCKS) * 256 + tid;
        size_t GT = (size_t)(gridDim.x - SCORE_BLOCKS) * 256;
        for (size_t k = gt; k < n4tot; k += GT)
            __builtin_nontemporal_store(z4, &out4[k]);
    }
}

// --- K2: block-owned columns — scan + bin + softmax + scattered dword writes ---
__global__ void __launch_bounds__(TPB) k2_all(
    const int* __restrict__ edges, const float* __restrict__ values,
    const float4* __restrict__ s_src4, const float4* __restrict__ s_dst4,
    const float* __restrict__ lin_w, const float* __restrict__ lin_b,
    float* __restrict__ out, int N, int E)
{
    __shared__ int cnt[CPB];
    __shared__ int lr[CPB][CAP];      // row index
    __shared__ float lnv[CPB][CAP];   // new value
    __shared__ float lav[CPB][CAP];   // original a-value
    __shared__ float lfin[CPB][CAP];  // final softmax value

    int tid = threadIdx.x;
    int c0 = blockIdx.x * CPB;
    if (tid < CPB) cnt[tid] = 0;
    __syncthreads();

    float lw0 = lin_w[0], lw1 = lin_w[1], lw2 = lin_w[2], lw3 = lin_w[3];
    float lb = lin_b[0];

    // --- phase B: int4 scan of dst; bin owned edges with logits ---
    const int* dst = edges + (size_t)E;
    auto process = [&](int c, int e) {
        unsigned rel = (unsigned)(c - c0);
        if (rel < (unsigned)CPB) {
            int r = edges[e];
            if ((unsigned)r < (unsigned)N) {
                float4 ss = s_src4[r];
                float4 sd = s_dst4[c];
                float a0 = ss.x + sd.x, a1 = ss.y + sd.y;
                float a2 = ss.z + sd.z, a3 = ss.w + sd.w;
                a0 = a0 >= 0.f ? a0 : ALPHA * a0;
                a1 = a1 >= 0.f ? a1 : ALPHA * a1;
                a2 = a2 >= 0.f ? a2 : ALPHA * a2;
                a3 = a3 >= 0.f ? a3 : ALPHA * a3;
                float mt = lb + a0 * lw0 + a1 * lw1 + a2 * lw2 + a3 * lw3;
                float av = values[e];
                int pos = atomicAdd(&cnt[rel], 1);   // LDS atomic (block-local)
                if (pos < CAP) {
                    lr[rel][pos] = r;
                    lnv[rel][pos] = av * mt;
                    lav[rel][pos] = av;
                }
            }
        }
    };
    int nq = E >> 2;
    const int4* dst4 = (const int4*)dst;
    for (int i = tid; i < nq; i += TPB) {
        int4 q = dst4[i];
        int e = i << 2;
        process(q.x, e);
        process(q.y, e + 1);
        process(q.z, e + 2);
        process(q.w, e + 3);
    }
    for (int e = (nq << 2) + tid; e < E; e += TPB) process(dst[e], e);
    __syncthreads();

    // --- phase C: per-column softmax (16 waves x 2 cols) -> lfin ---
    int wave = tid >> 6, lane = tid & 63;
    for (int q = wave; q < CPB; q += TPB / 64) {
        int m = cnt[q];
        if (m > CAP) m = CAP;
        if (m == 0) {
            // empty column (P ~ e^-32): uniform softmax, direct write
            float u = 1.0f / (float)N;
            int j = c0 + q;
            for (int i = lane; i < N; i += 64) out[(size_t)i * N + j] = u;
            continue;
        }
        if (m <= 64) {
            bool mine = lane < m;
            int rr;
            float vv, aav;
            if (mine) {
                rr = lr[q][lane];
                vv = lnv[q][lane];
                aav = lav[q][lane];
            } else {
                rr = -1 - lane;   // unique sentinels
                vv = 0.f;
                aav = 0.f;
            }
            float dsum = 0.f, asum = 0.f;
            bool first = true;
            for (int l = 0; l < m; ++l) {
                int rl = __shfl(rr, l);
                float vl = __shfl(vv, l);
                float al = __shfl(aav, l);
                if (rl == rr) {
                    dsum += vl;
                    asum += al;
                    if (l < lane) first = false;
                }
            }
            float mask = (asum == 1.0f) ? 0.f : asum;   // a_dense==1 -> 0, else count
            float val = dsum + mask;
            float lmax = (mine && first) ? val : -INFINITY;
#pragma unroll
            for (int off = 32; off; off >>= 1) lmax = fmaxf(lmax, __shfl_xor(lmax, off));
            float ex = (mine && first) ? expf(val - lmax) : 0.f;   // each group once
            float lsum = ex;
#pragma unroll
            for (int off = 32; off; off >>= 1) lsum += __shfl_xor(lsum, off);
            float inv = 1.0f / lsum;
            // dup group members hold identical val -> idempotent
            if (mine) lfin[q][lane] = expf(val - lmax) * inv;
        } else {
            // robust path (64 < m <= CAP): O(m^2) over LDS lists
            float lmax = -INFINITY;
            for (int k = lane; k < m; k += 64) {
                int rk = lr[q][k];
                bool first = true;
                float ds = 0.f, as = 0.f;
                for (int l = 0; l < m; ++l) {
                    if (lr[q][l] == rk) {
                        if (l < k) first = false;
                        ds += lnv[q][l];
                        as += lav[q][l];
                    }
                }
                if (first) {
                    float mk = (as == 1.0f) ? 0.f : as;
                    lmax = fmaxf(lmax, ds + mk);
                }
            }
#pragma unroll
            for (int off = 32; off; off >>= 1) lmax = fmaxf(lmax, __shfl_xor(lmax, off));
            float lsum = 0.f;
            for (int k = lane; k < m; k += 64) {
                int rk = lr[q][k];
                bool first = true;
                float ds = 0.f, as = 0.f;
                for (int l = 0; l < m; ++l) {
                    if (lr[q][l] == rk) {
                        if (l < k) first = false;
                        ds += lnv[q][l];
                        as += lav[q][l];
                    }
                }
                if (first) {
                    float mk = (as == 1.0f) ? 0.f : as;
                    lsum += expf(ds + mk - lmax);
                }
            }
#pragma unroll
            for (int off = 32; off; off >>= 1) lsum += __shfl_xor(lsum, off);
            float inv = 1.0f / lsum;
            for (int k = lane; k < m; k += 64) {
                int rk = lr[q][k];
                float ds = 0.f, as = 0.f;
                for (int l = 0; l < m; ++l) {
                    if (lr[q][l] == rk) {
                        ds += lnv[q][l];
                        as += lav[q][l];
                    }
                }
                float mk = (as == 1.0f) ? 0.f : as;
                lfin[q][k] = expf(ds + mk - lmax) * inv;   // idempotent for dups
            }
        }
    }
    __syncthreads();

    // --- phase D: scattered dword writes into pre-zeroed output (R7-proven) ---
    for (int s = tid; s < CPB * CAP; s += TPB) {
        int col = s >> 7, slot = s & (CAP - 1);
        int m = cnt[col];
        if (m > CAP) m = CAP;
        if (slot < m)
            out[(size_t)lr[col][slot] * N + (c0 + col)] = lfin[col][slot];
    }
}

extern "C" void kernel_launch(void* const* d_in, const int* in_sizes, int n_in,
                              void* d_out, int out_size, void* d_ws, size_t ws_size,
                              hipStream_t stream) {
    const float* x = (const float*)d_in[0];
    const int* edges = (const int*)d_in[1];      // harness: integer inputs are int32
    const float* values = (const float*)d_in[2];
    const float* W = (const float*)d_in[3];
    const float* a = (const float*)d_in[4];
    const float* lin_w = (const float*)d_in[5];
    const float* lin_b = (const float*)d_in[6];
    float* out = (float*)d_out;

    int N = in_sizes[0] / S;   // 8192
    int E = in_sizes[2];       // 262144

    // workspace carve (256B-aligned slabs)
    char* wsb = (char*)d_ws;
    size_t off = 0;
    auto alloc = [&](size_t bytes) -> void* {
        void* p = wsb + off;
        off += (bytes + 255) & ~(size_t)255;
        return p;
    };
    float4* s_src4 = (float4*)alloc((size_t)N * 16);
    float4* s_dst4 = (float4*)alloc((size_t)N * 16);

    size_t n4tot = (size_t)N * N / 4;
    k1_prep<<<SCORE_BLOCKS + 4096, 256, 0, stream>>>(
        x, W, a, s_src4, s_dst4, (vf4*)out, N, n4tot);
    k2_all<<<(N + CPB - 1) / CPB, TPB, 0, stream>>>(
        edges, values, s_src4, s_dst4, lin_w, lin_b, out, N, E);
}

// Round 13
// 143.990 us; speedup vs baseline: 1.0717x; 1.0717x over previous
//
#include <hip/hip_runtime.h>
#include <math.h>

// MultiHeadsGATLayer — algebraic reduction, 3 dispatches.
//   s_src[h][n] = x[n] . (W_heads[h] @ a_src[h]),  s_dst likewise
//   atts = lrelu(s_src[e0]+s_dst[e1]); mt = sum_h atts*lin_w + lin_b
//   out = colwise sparse softmax; non-edge cells exactly 0 (f32 underflow).
// D1: hipMemsetAsync zero of the 268MB output — fill engine does full-line
//     no-RFO writes at ~7TB/s (measured on the harness's own 1GiB fills);
//     beats both plain-store (~RFO) and NT-store (R11/R12 regression) zeroing.
// D2: k1_scores (32 blocks, ~3us).
// D3: k2_all (R12, unchanged): block owns 32 columns — int4 dst scan at
//     1024thr, LDS binning, shuffle-dedup softmax, scattered dword writes
//     into the pre-zeroed output. No global atomics/fences (R4/R9 lesson).

#define ALPHA 0.2f
constexpr int S = 128;
constexpr int O = 64;
constexpr int H = 4;
constexpr int CAP = 128;    // slots per column (degree ~ Poisson(32))
constexpr int CPB = 32;     // columns per K2 block
constexpr int TPB = 1024;   // K2 threads per block

// --- K1: per-node scores (head-major float4) ---
__global__ void __launch_bounds__(256) k1_scores(
    const float* __restrict__ x, const float* __restrict__ W, const float* __restrict__ a,
    float4* __restrict__ s_src4, float4* __restrict__ s_dst4, int N)
{
    __shared__ float wsbuf[2 * H * S];
    int tid = threadIdx.x;
    for (int t = tid; t < 2 * H * S; t += 256) {
        int which = t / (H * S);           // 0 = src half, 1 = dst half
        int hs = t % (H * S);
        int h = hs / S, s = hs % S;
        const float* Wr = W + ((size_t)h * S + s) * O;
        const float* av = a + h * 2 * O + which * O;
        float acc = 0.f;
        for (int o = 0; o < O; ++o) acc += Wr[o] * av[o];
        wsbuf[t] = acc;
    }
    __syncthreads();
    int n = blockIdx.x * 256 + tid;
    if (n >= N) return;
    const float* wsrc = wsbuf;
    const float* wdst = wsbuf + H * S;
    const float4* xr = (const float4*)(x + (size_t)n * S);
    float accs[H] = {0, 0, 0, 0}, accd[H] = {0, 0, 0, 0};
    for (int i = 0; i < S / 4; ++i) {
        float4 v = xr[i];
#pragma unroll
        for (int h = 0; h < H; ++h) {
            const float* p = wsrc + h * S + i * 4;
            const float* q = wdst + h * S + i * 4;
            accs[h] += v.x * p[0] + v.y * p[1] + v.z * p[2] + v.w * p[3];
            accd[h] += v.x * q[0] + v.y * q[1] + v.z * q[2] + v.w * q[3];
        }
    }
    s_src4[n] = make_float4(accs[0], accs[1], accs[2], accs[3]);
    s_dst4[n] = make_float4(accd[0], accd[1], accd[2], accd[3]);
}

// --- K2: block-owned columns — scan + bin + softmax + scattered dword writes ---
__global__ void __launch_bounds__(TPB) k2_all(
    const int* __restrict__ edges, const float* __restrict__ values,
    const float4* __restrict__ s_src4, const float4* __restrict__ s_dst4,
    const float* __restrict__ lin_w, const float* __restrict__ lin_b,
    float* __restrict__ out, int N, int E)
{
    __shared__ int cnt[CPB];
    __shared__ int lr[CPB][CAP];      // row index
    __shared__ float lnv[CPB][CAP];   // new value
    __shared__ float lav[CPB][CAP];   // original a-value
    __shared__ float lfin[CPB][CAP];  // final softmax value

    int tid = threadIdx.x;
    int c0 = blockIdx.x * CPB;
    if (tid < CPB) cnt[tid] = 0;
    __syncthreads();

    float lw0 = lin_w[0], lw1 = lin_w[1], lw2 = lin_w[2], lw3 = lin_w[3];
    float lb = lin_b[0];

    // --- phase B: int4 scan of dst; bin owned edges with logits ---
    const int* dst = edges + (size_t)E;
    auto process = [&](int c, int e) {
        unsigned rel = (unsigned)(c - c0);
        if (rel < (unsigned)CPB) {
            int r = edges[e];
            if ((unsigned)r < (unsigned)N) {
                float4 ss = s_src4[r];
                float4 sd = s_dst4[c];
                float a0 = ss.x + sd.x, a1 = ss.y + sd.y;
                float a2 = ss.z + sd.z, a3 = ss.w + sd.w;
                a0 = a0 >= 0.f ? a0 : ALPHA * a0;
                a1 = a1 >= 0.f ? a1 : ALPHA * a1;
                a2 = a2 >= 0.f ? a2 : ALPHA * a2;
                a3 = a3 >= 0.f ? a3 : ALPHA * a3;
                float mt = lb + a0 * lw0 + a1 * lw1 + a2 * lw2 + a3 * lw3;
                float av = values[e];
                int pos = atomicAdd(&cnt[rel], 1);   // LDS atomic (block-local)
                if (pos < CAP) {
                    lr[rel][pos] = r;
                    lnv[rel][pos] = av * mt;
                    lav[rel][pos] = av;
                }
            }
        }
    };
    int nq = E >> 2;
    const int4* dst4 = (const int4*)dst;
    for (int i = tid; i < nq; i += TPB) {
        int4 q = dst4[i];
        int e = i << 2;
        process(q.x, e);
        process(q.y, e + 1);
        process(q.z, e + 2);
        process(q.w, e + 3);
    }
    for (int e = (nq << 2) + tid; e < E; e += TPB) process(dst[e], e);
    __syncthreads();

    // --- phase C: per-column softmax (16 waves x 2 cols) -> lfin ---
    int wave = tid >> 6, lane = tid & 63;
    for (int q = wave; q < CPB; q += TPB / 64) {
        int m = cnt[q];
        if (m > CAP) m = CAP;
        if (m == 0) {
            // empty column (P ~ e^-32): uniform softmax, direct write
            float u = 1.0f / (float)N;
            int j = c0 + q;
            for (int i = lane; i < N; i += 64) out[(size_t)i * N + j] = u;
            continue;
        }
        if (m <= 64) {
            bool mine = lane < m;
            int rr;
            float vv, aav;
            if (mine) {
                rr = lr[q][lane];
                vv = lnv[q][lane];
                aav = lav[q][lane];
            } else {
                rr = -1 - lane;   // unique sentinels
                vv = 0.f;
                aav = 0.f;
            }
            float dsum = 0.f, asum = 0.f;
            bool first = true;
            for (int l = 0; l < m; ++l) {
                int rl = __shfl(rr, l);
                float vl = __shfl(vv, l);
                float al = __shfl(aav, l);
                if (rl == rr) {
                    dsum += vl;
                    asum += al;
                    if (l < lane) first = false;
                }
            }
            float mask = (asum == 1.0f) ? 0.f : asum;   // a_dense==1 -> 0, else count
            float val = dsum + mask;
            float lmax = (mine && first) ? val : -INFINITY;
#pragma unroll
            for (int off = 32; off; off >>= 1) lmax = fmaxf(lmax, __shfl_xor(lmax, off));
            float ex = (mine && first) ? expf(val - lmax) : 0.f;   // each group once
            float lsum = ex;
#pragma unroll
            for (int off = 32; off; off >>= 1) lsum += __shfl_xor(lsum, off);
            float inv = 1.0f / lsum;
            // dup group members hold identical val -> idempotent
            if (mine) lfin[q][lane] = expf(val - lmax) * inv;
        } else {
            // robust path (64 < m <= CAP): O(m^2) over LDS lists
            float lmax = -INFINITY;
            for (int k = lane; k < m; k += 64) {
                int rk = lr[q][k];
                bool first = true;
                float ds = 0.f, as = 0.f;
                for (int l = 0; l < m; ++l) {
                    if (lr[q][l] == rk) {
                        if (l < k) first = false;
                        ds += lnv[q][l];
                        as += lav[q][l];
                    }
                }
                if (first) {
                    float mk = (as == 1.0f) ? 0.f : as;
                    lmax = fmaxf(lmax, ds + mk);
                }
            }
#pragma unroll
            for (int off = 32; off; off >>= 1) lmax = fmaxf(lmax, __shfl_xor(lmax, off));
            float lsum = 0.f;
            for (int k = lane; k < m; k += 64) {
                int rk = lr[q][k];
                bool first = true;
                float ds = 0.f, as = 0.f;
                for (int l = 0; l < m; ++l) {
                    if (lr[q][l] == rk) {
                        if (l < k) first = false;
                        ds += lnv[q][l];
                        as += lav[q][l];
                    }
                }
                if (first) {
                    float mk = (as == 1.0f) ? 0.f : as;
                    lsum += expf(ds + mk - lmax);
                }
            }
#pragma unroll
            for (int off = 32; off; off >>= 1) lsum += __shfl_xor(lsum, off);
            float inv = 1.0f / lsum;
            for (int k = lane; k < m; k += 64) {
                int rk = lr[q][k];
                float ds = 0.f, as = 0.f;
                for (int l = 0; l < m; ++l) {
                    if (lr[q][l] == rk) {
                        ds += lnv[q][l];
                        as += lav[q][l];
                    }
                }
                float mk = (as == 1.0f) ? 0.f : as;
                lfin[q][k] = expf(ds + mk - lmax) * inv;   // idempotent for dups
            }
        }
    }
    __syncthreads();

    // --- phase D: scattered dword writes into pre-zeroed output (R7-proven) ---
    for (int s = tid; s < CPB * CAP; s += TPB) {
        int col = s >> 7, slot = s & (CAP - 1);
        int m = cnt[col];
        if (m > CAP) m = CAP;
        if (slot < m)
            out[(size_t)lr[col][slot] * N + (c0 + col)] = lfin[col][slot];
    }
}

extern "C" void kernel_launch(void* const* d_in, const int* in_sizes, int n_in,
                              void* d_out, int out_size, void* d_ws, size_t ws_size,
                              hipStream_t stream) {
    const float* x = (const float*)d_in[0];
    const int* edges = (const int*)d_in[1];      // harness: integer inputs are int32
    const float* values = (const float*)d_in[2];
    const float* W = (const float*)d_in[3];
    const float* a = (const float*)d_in[4];
    const float* lin_w = (const float*)d_in[5];
    const float* lin_b = (const float*)d_in[6];
    float* out = (float*)d_out;

    int N = in_sizes[0] / S;   // 8192
    int E = in_sizes[2];       // 262144

    // workspace carve (256B-aligned slabs)
    char* wsb = (char*)d_ws;
    size_t off = 0;
    auto alloc = [&](size_t bytes) -> void* {
        void* p = wsb + off;
        off += (bytes + 255) & ~(size_t)255;
        return p;
    };
    float4* s_src4 = (float4*)alloc((size_t)N * 16);
    float4* s_dst4 = (float4*)alloc((size_t)N * 16);

    // D1: fill-engine zero of the output (no-RFO full-line writes, ~7 TB/s)
    hipMemsetAsync(out, 0, (size_t)N * N * sizeof(float), stream);
    // D2: scores
    k1_scores<<<(N + 255) / 256, 256, 0, stream>>>(x, W, a, s_src4, s_dst4, N);
    // D3: fused scan + softmax + scattered writes
    k2_all<<<(N + CPB - 1) / CPB, TPB, 0, stream>>>(
        edges, values, s_src4, s_dst4, lin_w, lin_b, out, N, E);
}

// Round 14
// 142.523 us; speedup vs baseline: 1.0827x; 1.0103x over previous
//
#include <hip/hip_runtime.h>
#include <math.h>

// MultiHeadsGATLayer — algebraic reduction, 2 dispatches, proven components only.
//   s_src[h][n] = x[n] . (W_heads[h] @ a_src[h]),  s_dst likewise
//   atts = lrelu(s_src[e0]+s_dst[e1]); mt = sum_h atts*lin_w + lin_b
//   out = colwise sparse softmax; non-edge cells exactly 0 (f32 underflow).
// Measured zeroing hierarchy (R7 vs R11/R12 vs R13): PLAIN grid-stride float4
// stores ~5.3TB/s > NT stores ~= in-loop memset ~1.7-3TB/s. So:
// K1: R7's plain-store zero-stream (2048 blocks) + scores in first 32 blocks.
// K2: R12's fused scan+bin+softmax+scattered-dword-writes (block owns 32 cols,
//     1024 thr, LDS-only atomics). No global atomics/fences (R4/R9 lesson).

#define ALPHA 0.2f
constexpr int S = 128;
constexpr int O = 64;
constexpr int H = 4;
constexpr int CAP = 128;          // slots per column (degree ~ Poisson(32))
constexpr int CPB = 32;           // columns per K2 block
constexpr int TPB = 1024;         // K2 threads per block
constexpr int SCORE_BLOCKS = 32;  // ceil(N/256)
constexpr int K1_BLOCKS = 2048;   // R7-proven zero-stream geometry

// --- K1: plain-store zero-stream + per-node scores ---
__global__ void __launch_bounds__(256) k1_zero_scores(
    const float* __restrict__ x, const float* __restrict__ W, const float* __restrict__ a,
    float4* __restrict__ s_src4, float4* __restrict__ s_dst4,
    float4* __restrict__ out4, int N, size_t n4tot)
{
    int tid = threadIdx.x;
    int gt = blockIdx.x * 256 + tid;

    if (blockIdx.x < (unsigned)SCORE_BLOCKS) {
        __shared__ float wsbuf[2 * H * S];
        for (int t = tid; t < 2 * H * S; t += 256) {
            int which = t / (H * S);           // 0 = src half, 1 = dst half
            int hs = t % (H * S);
            int h = hs / S, s = hs % S;
            const float* Wr = W + ((size_t)h * S + s) * O;
            const float* av = a + h * 2 * O + which * O;
            float acc = 0.f;
            for (int o = 0; o < O; ++o) acc += Wr[o] * av[o];
            wsbuf[t] = acc;
        }
        __syncthreads();
        int n = gt;
        if (n < N) {
            const float* wsrc = wsbuf;
            const float* wdst = wsbuf + H * S;
            const float4* xr = (const float4*)(x + (size_t)n * S);
            float accs[H] = {0, 0, 0, 0}, accd[H] = {0, 0, 0, 0};
            for (int i = 0; i < S / 4; ++i) {
                float4 v = xr[i];
#pragma unroll
                for (int h = 0; h < H; ++h) {
                    const float* p = wsrc + h * S + i * 4;
                    const float* q = wdst + h * S + i * 4;
                    accs[h] += v.x * p[0] + v.y * p[1] + v.z * p[2] + v.w * p[3];
                    accd[h] += v.x * q[0] + v.y * q[1] + v.z * q[2] + v.w * q[3];
                }
            }
            s_src4[n] = make_float4(accs[0], accs[1], accs[2], accs[3]);
            s_dst4[n] = make_float4(accd[0], accd[1], accd[2], accd[3]);
        }
    }

    // zero-stream: all blocks, grid-stride, PLAIN float4 stores (R7-proven)
    const float4 z4 = make_float4(0.f, 0.f, 0.f, 0.f);
    size_t GT = (size_t)gridDim.x * 256;
    for (size_t k = gt; k < n4tot; k += GT) out4[k] = z4;
}

// --- K2: block-owned columns — scan + bin + softmax + scattered dword writes ---
__global__ void __launch_bounds__(TPB) k2_all(
    const int* __restrict__ edges, const float* __restrict__ values,
    const float4* __restrict__ s_src4, const float4* __restrict__ s_dst4,
    const float* __restrict__ lin_w, const float* __restrict__ lin_b,
    float* __restrict__ out, int N, int E)
{
    __shared__ int cnt[CPB];
    __shared__ int lr[CPB][CAP];      // row index
    __shared__ float lnv[CPB][CAP];   // new value
    __shared__ float lav[CPB][CAP];   // original a-value
    __shared__ float lfin[CPB][CAP];  // final softmax value

    int tid = threadIdx.x;
    int c0 = blockIdx.x * CPB;
    if (tid < CPB) cnt[tid] = 0;
    __syncthreads();

    float lw0 = lin_w[0], lw1 = lin_w[1], lw2 = lin_w[2], lw3 = lin_w[3];
    float lb = lin_b[0];

    // --- phase B: int4 scan of dst; bin owned edges with logits ---
    const int* dst = edges + (size_t)E;
    auto process = [&](int c, int e) {
        unsigned rel = (unsigned)(c - c0);
        if (rel < (unsigned)CPB) {
            int r = edges[e];
            if ((unsigned)r < (unsigned)N) {
                float4 ss = s_src4[r];
                float4 sd = s_dst4[c];
                float a0 = ss.x + sd.x, a1 = ss.y + sd.y;
                float a2 = ss.z + sd.z, a3 = ss.w + sd.w;
                a0 = a0 >= 0.f ? a0 : ALPHA * a0;
                a1 = a1 >= 0.f ? a1 : ALPHA * a1;
                a2 = a2 >= 0.f ? a2 : ALPHA * a2;
                a3 = a3 >= 0.f ? a3 : ALPHA * a3;
                float mt = lb + a0 * lw0 + a1 * lw1 + a2 * lw2 + a3 * lw3;
                float av = values[e];
                int pos = atomicAdd(&cnt[rel], 1);   // LDS atomic (block-local)
                if (pos < CAP) {
                    lr[rel][pos] = r;
                    lnv[rel][pos] = av * mt;
                    lav[rel][pos] = av;
                }
            }
        }
    };
    int nq = E >> 2;
    const int4* dst4 = (const int4*)dst;
    for (int i = tid; i < nq; i += TPB) {
        int4 q = dst4[i];
        int e = i << 2;
        process(q.x, e);
        process(q.y, e + 1);
        process(q.z, e + 2);
        process(q.w, e + 3);
    }
    for (int e = (nq << 2) + tid; e < E; e += TPB) process(dst[e], e);
    __syncthreads();

    // --- phase C: per-column softmax (16 waves x 2 cols) -> lfin ---
    int wave = tid >> 6, lane = tid & 63;
    for (int q = wave; q < CPB; q += TPB / 64) {
        int m = cnt[q];
        if (m > CAP) m = CAP;
        if (m == 0) {
            // empty column (P ~ e^-32): uniform softmax, direct write
            float u = 1.0f / (float)N;
            int j = c0 + q;
            for (int i = lane; i < N; i += 64) out[(size_t)i * N + j] = u;
            continue;
        }
        if (m <= 64) {
            bool mine = lane < m;
            int rr;
            float vv, aav;
            if (mine) {
                rr = lr[q][lane];
                vv = lnv[q][lane];
                aav = lav[q][lane];
            } else {
                rr = -1 - lane;   // unique sentinels
                vv = 0.f;
                aav = 0.f;
            }
            float dsum = 0.f, asum = 0.f;
            bool first = true;
            for (int l = 0; l < m; ++l) {
                int rl = __shfl(rr, l);
                float vl = __shfl(vv, l);
                float al = __shfl(aav, l);
                if (rl == rr) {
                    dsum += vl;
                    asum += al;
                    if (l < lane) first = false;
                }
            }
            float mask = (asum == 1.0f) ? 0.f : asum;   // a_dense==1 -> 0, else count
            float val = dsum + mask;
            float lmax = (mine && first) ? val : -INFINITY;
#pragma unroll
            for (int off = 32; off; off >>= 1) lmax = fmaxf(lmax, __shfl_xor(lmax, off));
            float ex = (mine && first) ? expf(val - lmax) : 0.f;   // each group once
            float lsum = ex;
#pragma unroll
            for (int off = 32; off; off >>= 1) lsum += __shfl_xor(lsum, off);
            float inv = 1.0f / lsum;
            // dup group members hold identical val -> idempotent
            if (mine) lfin[q][lane] = expf(val - lmax) * inv;
        } else {
            // robust path (64 < m <= CAP): O(m^2) over LDS lists
            float lmax = -INFINITY;
            for (int k = lane; k < m; k += 64) {
                int rk = lr[q][k];
                bool first = true;
                float ds = 0.f, as = 0.f;
                for (int l = 0; l < m; ++l) {
                    if (lr[q][l] == rk) {
                        if (l < k) first = false;
                        ds += lnv[q][l];
                        as += lav[q][l];
                    }
                }
                if (first) {
                    float mk = (as == 1.0f) ? 0.f : as;
                    lmax = fmaxf(lmax, ds + mk);
                }
            }
#pragma unroll
            for (int off = 32; off; off >>= 1) lmax = fmaxf(lmax, __shfl_xor(lmax, off));
            float lsum = 0.f;
            for (int k = lane; k < m; k += 64) {
                int rk = lr[q][k];
                bool first = true;
                float ds = 0.f, as = 0.f;
                for (int l = 0; l < m; ++l) {
                    if (lr[q][l] == rk) {
                        if (l < k) first = false;
                        ds += lnv[q][l];
                        as += lav[q][l];
                    }
                }
                if (first) {
                    float mk = (as == 1.0f) ? 0.f : as;
                    lsum += expf(ds + mk - lmax);
                }
            }
#pragma unroll
            for (int off = 32; off; off >>= 1) lsum += __shfl_xor(lsum, off);
            float inv = 1.0f / lsum;
            for (int k = lane; k < m; k += 64) {
                int rk = lr[q][k];
                float ds = 0.f, as = 0.f;
                for (int l = 0; l < m; ++l) {
                    if (lr[q][l] == rk) {
                        ds += lnv[q][l];
                        as += lav[q][l];
                    }
                }
                float mk = (as == 1.0f) ? 0.f : as;
                lfin[q][k] = expf(ds + mk - lmax) * inv;   // idempotent for dups
            }
        }
    }
    __syncthreads();

    // --- phase D: scattered dword writes into pre-zeroed output (R7-proven) ---
    for (int s = tid; s < CPB * CAP; s += TPB) {
        int col = s >> 7, slot = s & (CAP - 1);
        int m = cnt[col];
        if (m > CAP) m = CAP;
        if (slot < m)
            out[(size_t)lr[col][slot] * N + (c0 + col)] = lfin[col][slot];
    }
}

extern "C" void kernel_launch(void* const* d_in, const int* in_sizes, int n_in,
                              void* d_out, int out_size, void* d_ws, size_t ws_size,
                              hipStream_t stream) {
    const float* x = (const float*)d_in[0];
    const int* edges = (const int*)d_in[1];      // harness: integer inputs are int32
    const float* values = (const float*)d_in[2];
    const float* W = (const float*)d_in[3];
    const float* a = (const float*)d_in[4];
    const float* lin_w = (const float*)d_in[5];
    const float* lin_b = (const float*)d_in[6];
    float* out = (float*)d_out;

    int N = in_sizes[0] / S;   // 8192
    int E = in_sizes[2];       // 262144

    // workspace carve (256B-aligned slabs)
    char* wsb = (char*)d_ws;
    size_t off = 0;
    auto alloc = [&](size_t bytes) -> void* {
        void* p = wsb + off;
        off += (bytes + 255) & ~(size_t)255;
        return p;
    };
    float4* s_src4 = (float4*)alloc((size_t)N * 16);
    float4* s_dst4 = (float4*)alloc((size_t)N * 16);

    size_t n4tot = (size_t)N * N / 4;
    k1_zero_scores<<<K1_BLOCKS, 256, 0, stream>>>(
        x, W, a, s_src4, s_dst4, (float4*)out, N, n4tot);
    k2_all<<<(N + CPB - 1) / CPB, TPB, 0, stream>>>(
        edges, values, s_src4, s_dst4, lin_w, lin_b, out, N, E);
}